// Round 6
// baseline (2929.838 us; speedup 1.0000x reference)
//
#include <hip/hip_runtime.h>

constexpr int Nn = 50000;
constexpr int Ee = 800000;
constexpr int Qq = 2000000;
constexpr int Gg = 64;
constexpr int Hh = 128;
constexpr int NB64 = (Nn + 63) / 64;

typedef short bf16x8 __attribute__((ext_vector_type(8)));
typedef float f32x4  __attribute__((ext_vector_type(4)));

__device__ __forceinline__ unsigned short f2bf(float f) {
    unsigned u = __builtin_bit_cast(unsigned, f);
    u += 0x7FFFu + ((u >> 16) & 1u);
    return (unsigned short)(u >> 16);
}
__device__ __forceinline__ float bf2f(unsigned short s) {
    unsigned u = ((unsigned)s) << 16;
    return __builtin_bit_cast(float, u);
}

// ---------------- counting sort ----------------
__global__ void k_hist(const int* __restrict__ idx, int n, int limit,
                       int* __restrict__ hist) {
    int i = blockIdx.x * blockDim.x + threadIdx.x;
    if (i < n) { int v = idx[i]; if (v < limit) atomicAdd(&hist[v], 1); }
}

__global__ __launch_bounds__(1024) void k_scan(const int* __restrict__ hist,
                                               int* __restrict__ cursor,
                                               int* __restrict__ total) {
    __shared__ int s[1024];
    const int tid = threadIdx.x;
    const int per = (Nn + 1023) / 1024;
    int start = tid * per, end = min(start + per, Nn);
    int sum = 0;
    for (int i = start; i < end; ++i) sum += hist[i];
    s[tid] = sum;
    __syncthreads();
    for (int off = 1; off < 1024; off <<= 1) {
        int v = (tid >= off) ? s[tid - off] : 0;
        __syncthreads();
        s[tid] += v;
        __syncthreads();
    }
    int base = s[tid] - sum;
    for (int i = start; i < end; ++i) {
        cursor[i] = base;
        base += hist[i];
    }
    if (tid == 1023 && total) *total = s[1023];
}

__global__ void k_scatter(const int* __restrict__ idx, int n, int limit,
                          int* __restrict__ cursor, int* __restrict__ perm) {
    int i = blockIdx.x * blockDim.x + threadIdx.x;
    if (i < n) {
        int v = idx[i];
        if (v < limit) { int p = atomicAdd(&cursor[v], 1); perm[p] = i; }
    }
}

// ---------------- fused per-layer weight transpose to bf16 ----------------
// layout within a layer's wbuf slice (bf16 elems):
//   [0,16384)       Wq1t : W_e1a rows 0..127   -> [128][128]
//   [16384,20480)   Wp2t : W_e1a rows 128..133 -> [128][32] zero-pad
//   [20480,36864)   We1bt: W_e1b               -> [128][128]
//   [36864,69632)   We2at: W_e2a               -> [128][256]
//   [69632,86016)   We2bt: W_e2b               -> [128][128]
//   [86016,118784)  Wnat : W_na                -> [128][256]
//   [118784,135168) Wnbt : W_nb                -> [128][128]
__global__ void k_wtall(const float* __restrict__ We1a, const float* __restrict__ We1b,
                        const float* __restrict__ We2a, const float* __restrict__ We2b,
                        const float* __restrict__ Wna,  const float* __restrict__ Wnb,
                        unsigned short* __restrict__ base) {
    int idx = blockIdx.x * blockDim.x + threadIdx.x;
    if (idx >= 135168) return;
    const float* src; int K, Kp, loc;
    if (idx < 16384)       { src = We1a;             K = 128; Kp = 128; loc = idx; }
    else if (idx < 20480)  { src = We1a + 128 * 128; K = 6;   Kp = 32;  loc = idx - 16384; }
    else if (idx < 36864)  { src = We1b;             K = 128; Kp = 128; loc = idx - 20480; }
    else if (idx < 69632)  { src = We2a;             K = 256; Kp = 256; loc = idx - 36864; }
    else if (idx < 86016)  { src = We2b;             K = 128; Kp = 128; loc = idx - 69632; }
    else if (idx < 118784) { src = Wna;              K = 256; Kp = 256; loc = idx - 86016; }
    else                   { src = Wnb;              K = 128; Kp = 128; loc = idx - 118784; }
    int n = loc / Kp, k = loc - n * Kp;
    base[idx] = (k < K) ? f2bf(src[(size_t)k * 128 + n]) : (unsigned short)0;
}

// ---------------- x -> bf16 h0 ----------------
__global__ void k_h0(const float* __restrict__ x, unsigned short* __restrict__ hb) {
    int idx = blockIdx.x * blockDim.x + threadIdx.x;
    if (idx < Nn * Hh) hb[idx] = f2bf(x[idx]);
}

// ---------------- GEMM building blocks (verified r2-r4 tile) ----------------
__device__ __forceinline__ void zacc(f32x4 acc[4][2]) {
#pragma unroll
    for (int rt = 0; rt < 4; ++rt)
#pragma unroll
        for (int ct = 0; ct < 2; ++ct)
            acc[rt][ct] = (f32x4){0.f, 0.f, 0.f, 0.f};
}

// C[64x128] += A_lds[64xKK] * Wt[128][KP]^T (Wt k-contiguous, k window at k_off)
template<int KK, int SA, int KP>
__device__ __forceinline__ void gemm64(const unsigned short* A,
                                       const unsigned short* __restrict__ Wt,
                                       int k_off, f32x4 acc[4][2]) {
    const int tid = threadIdx.x;
    const int lane = tid & 63;
    const int nb = (tid >> 6) * 32;
    const int rA = lane & 15;
    const int kg = lane >> 4;
#pragma unroll
    for (int ks = 0; ks < KK / 32; ++ks) {
        const int ka = ks * 32 + kg * 8;
        const int kb = k_off + ka;
        bf16x8 b0 = *(const bf16x8*)&Wt[(size_t)(nb + rA) * KP + kb];
        bf16x8 b1 = *(const bf16x8*)&Wt[(size_t)(nb + 16 + rA) * KP + kb];
#pragma unroll
        for (int rt = 0; rt < 4; ++rt) {
            bf16x8 a = *(const bf16x8*)&A[(rt * 16 + rA) * SA + ka];
            acc[rt][0] = __builtin_amdgcn_mfma_f32_16x16x32_bf16(a, b0, acc[rt][0], 0, 0, 0);
            acc[rt][1] = __builtin_amdgcn_mfma_f32_16x16x32_bf16(a, b1, acc[rt][1], 0, 0, 0);
        }
    }
}

__device__ __forceinline__ void store_acc(const f32x4 acc[4][2], unsigned short* out,
                                          int n0, int nmax) {
    const int tid = threadIdx.x;
    const int lane = tid & 63;
    const int nb = (tid >> 6) * 32;
    const int rA = lane & 15, kg = lane >> 4;
#pragma unroll
    for (int rt = 0; rt < 4; ++rt)
#pragma unroll
        for (int ct = 0; ct < 2; ++ct) {
            int col = nb + ct * 16 + rA;
#pragma unroll
            for (int i = 0; i < 4; ++i) {
                int n = n0 + rt * 16 + kg * 4 + i;
                if (n < nmax) out[(size_t)n * 128 + col] = f2bf(acc[rt][ct][i]);
            }
        }
}

// ---------------- k_pre: P1 = h*Wq1, Z1 = h*We2a[0:128], P2 = rbf*Wp2 ----------------
__global__ __launch_bounds__(256) void k_pre(
    const unsigned short* __restrict__ hb, const float* __restrict__ rbf,
    const unsigned short* __restrict__ wb,
    unsigned short* __restrict__ P1, unsigned short* __restrict__ Z1,
    unsigned short* __restrict__ P2)
{
    __shared__ unsigned short L[64 * 136];
    const int m0 = blockIdx.x * 64;
    const int tid = threadIdx.x;
    const unsigned short* Wq1t = wb;
    const unsigned short* Wp2t = wb + 16384;
    const unsigned short* We2at = wb + 36864;
    for (int i = tid; i < 64 * 16; i += 256) {
        int row = i >> 4, ch = i & 15;
        int n = min(m0 + row, Nn - 1);
        *(uint4*)&L[row * 136 + ch * 8] = *(const uint4*)&hb[(size_t)n * 128 + ch * 8];
    }
    __syncthreads();
    f32x4 acc[4][2];
    zacc(acc);
    gemm64<128, 136, 128>(L, Wq1t, 0, acc);
    store_acc(acc, P1, m0, Nn);
    zacc(acc);
    gemm64<128, 136, 256>(L, We2at, 0, acc);
    store_acc(acc, Z1, m0, Nn);
    __syncthreads();
    for (int i = tid; i < 64 * 32; i += 256) {
        int row = i >> 5, c = i & 31;
        int n = min(m0 + row, Nn - 1);
        float v = (c < 6) ? rbf[(size_t)n * 6 + c] : 0.f;
        L[row * 136 + c] = f2bf(v);
    }
    __syncthreads();
    zacc(acc);
    gemm64<32, 136, 32>(L, Wp2t, 0, acc);
    store_acc(acc, P2, m0, Nn);
}

// ---------------- k_quadlite: hidden=P1[l]+P2[k]+[cbf|sbf]*W34+b -> ReLU -> segsum Rq[k] ----------------
__global__ __launch_bounds__(256) void k_quadlite(
    const unsigned short* __restrict__ P1, const unsigned short* __restrict__ P2,
    const float* __restrict__ cbf, const float* __restrict__ sbf,
    const int* __restrict__ l_idx, const int* __restrict__ k_idx,
    const int* __restrict__ list, const int* __restrict__ cnt,
    const float* __restrict__ We1a_raw, const float* __restrict__ b_e1a,
    float* __restrict__ Rq)
{
    __shared__ float W34[12 * 128];
    __shared__ float bia[128];
    __shared__ float qv[128 * 12];
    __shared__ int rl[128], rk[128];
    const int tid = threadIdx.x;
    for (int i = tid; i < 12 * 128; i += 256) W34[i] = We1a_raw[134 * 128 + i];
    if (tid < 128) bia[tid] = b_e1a[tid];
    const int Qu = *cnt;
    const int r = tid >> 4;
    const int c0 = (tid & 15) * 8;
    for (int m0 = blockIdx.x * 128; m0 < Qu; m0 += gridDim.x * 128) {
        __syncthreads();
        if (tid < 128) {
            int m = m0 + tid;
            if (m < Qu) {
                int q = list[m];
                rl[tid] = l_idx[q];
                rk[tid] = k_idx[q];
#pragma unroll
                for (int k = 0; k < 6; ++k) qv[tid * 12 + k] = cbf[(size_t)q * 6 + k];
#pragma unroll
                for (int k = 0; k < 6; ++k) qv[tid * 12 + 6 + k] = sbf[(size_t)q * 6 + k];
            } else rk[tid] = -1;
        }
        __syncthreads();
        float t[8][8];
        int vl[8];
#pragma unroll
        for (int j = 0; j < 8; ++j) {
            int row = r * 8 + j;
            int d = rk[row];
            vl[j] = d;
            int ll = (d >= 0) ? rl[row] : 0;
            int dd = (d >= 0) ? d : 0;
            uint4 a = *(const uint4*)&P1[(size_t)ll * 128 + c0];
            uint4 b = *(const uint4*)&P2[(size_t)dd * 128 + c0];
            const unsigned short* ap = (const unsigned short*)&a;
            const unsigned short* bp = (const unsigned short*)&b;
#pragma unroll
            for (int k = 0; k < 8; ++k)
                t[j][k] = bia[c0 + k] + bf2f(ap[k]) + bf2f(bp[k]);
        }
#pragma unroll
        for (int kk = 0; kk < 12; ++kk) {
            float wv[8];
#pragma unroll
            for (int k = 0; k < 8; ++k) wv[k] = W34[kk * 128 + c0 + k];
#pragma unroll
            for (int j = 0; j < 8; ++j) {
                float qq = qv[(r * 8 + j) * 12 + kk];
#pragma unroll
                for (int k = 0; k < 8; ++k) t[j][k] = fmaf(qq, wv[k], t[j][k]);
            }
        }
        float s[8];
#pragma unroll
        for (int k = 0; k < 8; ++k) s[k] = 0.f;
        int cur = vl[0];
#pragma unroll
        for (int j = 0; j < 8; ++j) {
            int d = vl[j];
            if (d != cur) {
                if (cur >= 0) {
#pragma unroll
                    for (int k = 0; k < 8; ++k)
                        atomicAdd(&Rq[(size_t)cur * 128 + c0 + k], s[k]);
                }
#pragma unroll
                for (int k = 0; k < 8; ++k) s[k] = 0.f;
                cur = d;
            }
            if (d >= 0) {
#pragma unroll
                for (int k = 0; k < 8; ++k) s[k] += fmaxf(t[j][k], 0.f);
            }
        }
        if (cur >= 0) {
#pragma unroll
            for (int k = 0; k < 8; ++k)
                atomicAdd(&Rq[(size_t)cur * 128 + c0 + k], s[k]);
        }
    }
}

// ---------------- k_agg2z: T = Rq*We1b + cntq*b_e1b ; Z2 = T*We2a[128:256] ----------------
__global__ __launch_bounds__(256) void k_agg2z(
    const float* __restrict__ Rq, const int* __restrict__ cntq,
    const unsigned short* __restrict__ wb, const float* __restrict__ b_e1b,
    unsigned short* __restrict__ Z2)
{
    __shared__ unsigned short L[64 * 136];
    __shared__ int rc[64];
    const int m0 = blockIdx.x * 64;
    const int tid = threadIdx.x;
    const unsigned short* We1bt = wb + 20480;
    const unsigned short* We2at = wb + 36864;
    if (tid < 64) rc[tid] = (m0 + tid < Nn) ? cntq[m0 + tid] : 0;
    for (int i = tid; i < 64 * 32; i += 256) {
        int row = i >> 5, c = i & 31;
        int n = min(m0 + row, Nn - 1);
        float4 v = *(const float4*)&Rq[(size_t)n * 128 + c * 4];
        ushort4 o; o.x = f2bf(v.x); o.y = f2bf(v.y); o.z = f2bf(v.z); o.w = f2bf(v.w);
        *(ushort4*)&L[row * 136 + c * 4] = o;
    }
    __syncthreads();
    f32x4 acc[4][2];
    zacc(acc);
    gemm64<128, 136, 128>(L, We1bt, 0, acc);
    __syncthreads();
    {
        const int lane = tid & 63;
        const int nb = (tid >> 6) * 32;
        const int rA = lane & 15, kg = lane >> 4;
#pragma unroll
        for (int rt = 0; rt < 4; ++rt)
#pragma unroll
            for (int ct = 0; ct < 2; ++ct) {
                int col = nb + ct * 16 + rA;
                float bias = b_e1b[col];
#pragma unroll
                for (int i = 0; i < 4; ++i) {
                    int row = rt * 16 + kg * 4 + i;
                    L[row * 136 + col] = f2bf(acc[rt][ct][i] + (float)rc[row] * bias);
                }
            }
    }
    __syncthreads();
    zacc(acc);
    gemm64<128, 136, 256>(L, We2at, 128, acc);
    store_acc(acc, Z2, m0, Nn);
}

// ---------------- k_edgelite: Re[dst] += ReLU(Z1[src]+Z2[dst]+b_e2a) ----------------
__global__ __launch_bounds__(256) void k_edgelite(
    const unsigned short* __restrict__ Z1, const unsigned short* __restrict__ Z2,
    const int* __restrict__ src, const int* __restrict__ dst,
    const int* __restrict__ perm, const float* __restrict__ b_e2a,
    float* __restrict__ Re)
{
    __shared__ int rs[128], rd[128];
    __shared__ float bia[128];
    const int m0 = blockIdx.x * 128;      // Ee % 128 == 0
    const int tid = threadIdx.x;
    if (tid < 128) {
        int e = perm[m0 + tid];
        rs[tid] = src[e]; rd[tid] = dst[e];
        bia[tid] = b_e2a[tid];
    }
    __syncthreads();
    const int r = tid >> 4;
    const int c0 = (tid & 15) * 8;
    float s[8];
#pragma unroll
    for (int k = 0; k < 8; ++k) s[k] = 0.f;
    int cur = rd[r * 8];
#pragma unroll
    for (int j = 0; j < 8; ++j) {
        int row = r * 8 + j;
        int d = rd[row];
        uint4 a = *(const uint4*)&Z1[(size_t)rs[row] * 128 + c0];
        uint4 b = *(const uint4*)&Z2[(size_t)d * 128 + c0];
        if (d != cur) {
#pragma unroll
            for (int k = 0; k < 8; ++k)
                atomicAdd(&Re[(size_t)cur * 128 + c0 + k], s[k]);
#pragma unroll
            for (int k = 0; k < 8; ++k) s[k] = 0.f;
            cur = d;
        }
        const unsigned short* ap = (const unsigned short*)&a;
        const unsigned short* bp = (const unsigned short*)&b;
#pragma unroll
        for (int k = 0; k < 8; ++k)
            s[k] += fmaxf(bia[c0 + k] + bf2f(ap[k]) + bf2f(bp[k]), 0.f);
    }
#pragma unroll
    for (int k = 0; k < 8; ++k)
        atomicAdd(&Re[(size_t)cur * 128 + c0 + k], s[k]);
}

// ---------------- k_nodeNew: U=Re*We2b+deg*b2; V=U*Wna[128:]+h*Wna[:128]; h'=ReLU(V+b)*Wnb+b ----------------
__global__ __launch_bounds__(256) void k_nodeNew(
    const float* __restrict__ Re, const int* __restrict__ deg,
    const unsigned short* __restrict__ hb,
    const unsigned short* __restrict__ wb,
    const float* __restrict__ b_e2b, const float* __restrict__ b_na,
    const float* __restrict__ b_nb,
    unsigned short* __restrict__ hnew)
{
    __shared__ unsigned short L[64 * 136];
    __shared__ int rc[64];
    const int m0 = blockIdx.x * 64;
    const int tid = threadIdx.x;
    const unsigned short* We2bt = wb + 69632;
    const unsigned short* Wnat  = wb + 86016;
    const unsigned short* Wnbt  = wb + 118784;
    const int lane = tid & 63;
    const int nb = (tid >> 6) * 32;
    const int rA = lane & 15, kg = lane >> 4;
    if (tid < 64) rc[tid] = (m0 + tid < Nn) ? deg[m0 + tid] : 0;
    for (int i = tid; i < 64 * 32; i += 256) {
        int row = i >> 5, c = i & 31;
        int n = min(m0 + row, Nn - 1);
        float4 v = *(const float4*)&Re[(size_t)n * 128 + c * 4];
        ushort4 o; o.x = f2bf(v.x); o.y = f2bf(v.y); o.z = f2bf(v.z); o.w = f2bf(v.w);
        *(ushort4*)&L[row * 136 + c * 4] = o;
    }
    __syncthreads();
    f32x4 acc[4][2];
    zacc(acc);
    gemm64<128, 136, 128>(L, We2bt, 0, acc);     // U = Re*We2b
    __syncthreads();
#pragma unroll
    for (int rt = 0; rt < 4; ++rt)
#pragma unroll
        for (int ct = 0; ct < 2; ++ct) {
            int col = nb + ct * 16 + rA;
            float bias = b_e2b[col];
#pragma unroll
            for (int i = 0; i < 4; ++i) {
                int row = rt * 16 + kg * 4 + i;
                L[row * 136 + col] = f2bf(acc[rt][ct][i] + (float)rc[row] * bias);
            }
        }
    __syncthreads();
    f32x4 acc2[4][2];
    zacc(acc2);
    gemm64<128, 136, 256>(L, Wnat, 128, acc2);   // V = U*Wbot_n
    __syncthreads();
    for (int i = tid; i < 64 * 16; i += 256) {
        int row = i >> 4, ch = i & 15;
        int n = min(m0 + row, Nn - 1);
        *(uint4*)&L[row * 136 + ch * 8] = *(const uint4*)&hb[(size_t)n * 128 + ch * 8];
    }
    __syncthreads();
    gemm64<128, 136, 256>(L, Wnat, 0, acc2);     // V += h*Wtop_n
    __syncthreads();
#pragma unroll
    for (int rt = 0; rt < 4; ++rt)
#pragma unroll
        for (int ct = 0; ct < 2; ++ct) {
            int col = nb + ct * 16 + rA;
            float bias = b_na[col];
#pragma unroll
            for (int i = 0; i < 4; ++i) {
                int row = rt * 16 + kg * 4 + i;
                L[row * 136 + col] = f2bf(fmaxf(acc2[rt][ct][i] + bias, 0.f));
            }
        }
    __syncthreads();
    zacc(acc);
    gemm64<128, 136, 128>(L, Wnbt, 0, acc);      // hidden*Wnb
#pragma unroll
    for (int rt = 0; rt < 4; ++rt)
#pragma unroll
        for (int ct = 0; ct < 2; ++ct) {
            int col = nb + ct * 16 + rA;
            float bias = b_nb[col];
#pragma unroll
            for (int i = 0; i < 4; ++i) {
                int n = m0 + rt * 16 + kg * 4 + i;
                if (n < Nn)
                    hnew[(size_t)n * 128 + col] = f2bf(acc[rt][ct][i] + bias);
            }
        }
}

// ---------------- global mean pool: run-length segmented reduction ----------------
__global__ __launch_bounds__(256) void k_pool(const unsigned short* __restrict__ hb,
                                              const int* __restrict__ batch,
                                              float* __restrict__ pooled,
                                              float* __restrict__ cntg) {
    __shared__ int bseg[200];
    constexpr int CH = 196;
    const int start = blockIdx.x * CH;
    const int end = min(start + CH, Nn);
    if (start >= end) return;
    const int tid = threadIdx.x;
    for (int i = tid; i < end - start; i += 256) bseg[i] = batch[start + i];
    __syncthreads();
    const int j = tid & 127;
    const int rh = tid >> 7;
    float acc = 0.f, cacc = 0.f;
    int cur = -1;
    for (int n = start + rh; n < end; n += 2) {
        int g = bseg[n - start];
        if (g != cur) {
            if (cur >= 0) {
                atomicAdd(&pooled[cur * Hh + j], acc);
                if (j == 0) atomicAdd(&cntg[cur], cacc);
            }
            cur = g; acc = 0.f; cacc = 0.f;
        }
        acc += bf2f(hb[(size_t)n * Hh + j]);
        cacc += 1.f;
    }
    if (cur >= 0) {
        atomicAdd(&pooled[cur * Hh + j], acc);
        if (j == 0) atomicAdd(&cntg[cur], cacc);
    }
}

// ---------------- final per-graph MLP ----------------
__global__ __launch_bounds__(128) void k_final(
    const float* __restrict__ pooled, const float* __restrict__ cntg,
    const float* __restrict__ Woa, const float* __restrict__ boa,
    const float* __restrict__ Wob, const float* __restrict__ bob,
    float* __restrict__ out)
{
    __shared__ float p[128];
    __shared__ float t[128];
    __shared__ float red[128];
    const int g = blockIdx.x;
    const int j = threadIdx.x;
    float c = fmaxf(cntg[g], 1.f);
    p[j] = fmaxf(pooled[g * Hh + j] / c, 0.f);
    __syncthreads();
    float acc = boa[j];
    for (int d = 0; d < Hh; ++d) acc = fmaf(p[d], Woa[d * Hh + j], acc);
    t[j] = fmaxf(acc, 0.f);
    __syncthreads();
    red[j] = t[j] * Wob[j];
    __syncthreads();
    for (int s = 64; s > 0; s >>= 1) {
        if (j < s) red[j] += red[j + s];
        __syncthreads();
    }
    if (j == 0) out[g] = red[0] + bob[0];
}

extern "C" void kernel_launch(void* const* d_in, const int* in_sizes, int n_in,
                              void* d_out, int out_size, void* d_ws, size_t ws_size,
                              hipStream_t stream) {
    const float* x     = (const float*)d_in[0];
    const float* rbf   = (const float*)d_in[1];
    const float* cbf   = (const float*)d_in[2];
    const float* sbf   = (const float*)d_in[3];
    const int*   eidx  = (const int*)d_in[4];
    const int*   l_idx = (const int*)d_in[5];
    const int*   k_idx = (const int*)d_in[6];
    const int*   batch = (const int*)d_in[7];
    const float* W_e1a = (const float*)d_in[8];
    const float* b_e1a = (const float*)d_in[9];
    const float* W_e1b = (const float*)d_in[10];
    const float* b_e1b = (const float*)d_in[11];
    const float* W_e2a = (const float*)d_in[12];
    const float* b_e2a = (const float*)d_in[13];
    const float* W_e2b = (const float*)d_in[14];
    const float* b_e2b = (const float*)d_in[15];
    const float* W_na  = (const float*)d_in[16];
    const float* b_na  = (const float*)d_in[17];
    const float* W_nb  = (const float*)d_in[18];
    const float* b_nb  = (const float*)d_in[19];
    const float* W_oa  = (const float*)d_in[20];
    const float* b_oa  = (const float*)d_in[21];
    const float* W_ob  = (const float*)d_in[22];
    const float* b_ob  = (const float*)d_in[23];

    const int* src = eidx;
    const int* dst = eidx + Ee;

    const size_t NHf = (size_t)Nn * Hh * sizeof(float);
    const size_t NHb = (size_t)Nn * Hh * sizeof(unsigned short);
    char* w = (char*)d_ws;
    unsigned short* hb0 = (unsigned short*)w; w += NHb;
    unsigned short* hb1 = (unsigned short*)w; w += NHb;
    unsigned short* P1  = (unsigned short*)w; w += NHb;   // reused as nothing else
    unsigned short* P2  = (unsigned short*)w; w += NHb;
    unsigned short* Z1  = (unsigned short*)w; w += NHb;
    unsigned short* Z2  = (unsigned short*)w; w += NHb;
    float* R      = (float*)w; w += NHf;                  // shared Rq / Re
    float* pooled = (float*)w; w += (size_t)Gg * Hh * sizeof(float);
    float* cntg   = (float*)w; w += (size_t)Gg * sizeof(float);
    int*   qlist  = (int*)w;   w += (size_t)Qq * sizeof(int);
    int*   perm_e = (int*)w;   w += (size_t)Ee * sizeof(int);
    int*   hist_e = (int*)w;   w += (size_t)Nn * sizeof(int);
    int*   hist_q = (int*)w;   w += (size_t)Nn * sizeof(int);
    int*   cursor = (int*)w;   w += (size_t)Nn * sizeof(int);
    int*   qcnt   = (int*)w;   w += 16;
    unsigned short* wbuf = (unsigned short*)w;            // 3 x 135168 bf16

    const size_t LSTRIDE = 135168;

    // --- counting sort: edges by dst (hist_e kept = in-degree) ---
    hipMemsetAsync(hist_e, 0, Nn * sizeof(int), stream);
    k_hist<<<(Ee + 255) / 256, 256, 0, stream>>>(dst, Ee, Nn, hist_e);
    k_scan<<<1, 1024, 0, stream>>>(hist_e, cursor, (int*)nullptr);
    k_scatter<<<(Ee + 255) / 256, 256, 0, stream>>>(dst, Ee, Nn, cursor, perm_e);
    // --- counting sort: quads by k_idx, fused compaction (hist_q kept = per-k count) ---
    hipMemsetAsync(hist_q, 0, Nn * sizeof(int), stream);
    k_hist<<<(Qq + 255) / 256, 256, 0, stream>>>(k_idx, Qq, Nn, hist_q);
    k_scan<<<1, 1024, 0, stream>>>(hist_q, cursor, qcnt);
    k_scatter<<<(Qq + 255) / 256, 256, 0, stream>>>(k_idx, Qq, Nn, cursor, qlist);

    k_h0<<<(Nn * Hh + 255) / 256, 256, 0, stream>>>(x, hb0);

    for (int p = 0; p < 3; ++p) {
        k_wtall<<<(135168 + 255) / 256, 256, 0, stream>>>(
            W_e1a + (size_t)p * 146 * 128, W_e1b + (size_t)p * 128 * 128,
            W_e2a + (size_t)p * 256 * 128, W_e2b + (size_t)p * 128 * 128,
            W_na  + (size_t)p * 256 * 128, W_nb  + (size_t)p * 128 * 128,
            wbuf + p * LSTRIDE);
    }

    unsigned short* bufs[2] = { hb0, hb1 };
    int cur = 0;
    for (int p = 0; p < 3; ++p) {
        const unsigned short* wb = wbuf + p * LSTRIDE;
        hipMemsetAsync(R, 0, NHf, stream);
        k_pre<<<NB64, 256, 0, stream>>>(bufs[cur], rbf, wb, P1, Z1, P2);
        k_quadlite<<<1024, 256, 0, stream>>>(P1, P2, cbf, sbf, l_idx, k_idx,
            qlist, qcnt, W_e1a + (size_t)p * 146 * 128, b_e1a + (size_t)p * 128, R);
        k_agg2z<<<NB64, 256, 0, stream>>>(R, hist_q, wb, b_e1b + (size_t)p * 128, Z2);
        hipMemsetAsync(R, 0, NHf, stream);
        k_edgelite<<<Ee / 128, 256, 0, stream>>>(Z1, Z2, src, dst, perm_e,
            b_e2a + (size_t)p * 128, R);
        k_nodeNew<<<NB64, 256, 0, stream>>>(R, hist_e, bufs[cur], wb,
            b_e2b + (size_t)p * 128, b_na + (size_t)p * 128, b_nb + (size_t)p * 128,
            bufs[cur ^ 1]);
        cur ^= 1;
    }
    hipMemsetAsync(pooled, 0, (size_t)Gg * Hh * sizeof(float), stream);
    hipMemsetAsync(cntg, 0, (size_t)Gg * sizeof(float), stream);
    k_pool<<<(Nn + 195) / 196, 256, 0, stream>>>(bufs[cur], batch, pooled, cntg);
    k_final<<<Gg, 128, 0, stream>>>(pooled, cntg, W_oa, b_oa, W_ob, b_ob, (float*)d_out);
}

// Round 7
// 729.009 us; speedup vs baseline: 4.0189x; 4.0189x over previous
//
#include <hip/hip_runtime.h>

constexpr int Nn = 50000;
constexpr int Ee = 800000;
constexpr int Qq = 2000000;
constexpr int Gg = 64;
constexpr int Hh = 128;
constexpr int NB64 = (Nn + 63) / 64;

typedef short bf16x8 __attribute__((ext_vector_type(8)));
typedef float f32x4  __attribute__((ext_vector_type(4)));

__device__ __forceinline__ unsigned short f2bf(float f) {
    unsigned u = __builtin_bit_cast(unsigned, f);
    u += 0x7FFFu + ((u >> 16) & 1u);
    return (unsigned short)(u >> 16);
}
__device__ __forceinline__ float bf2f(unsigned short s) {
    unsigned u = ((unsigned)s) << 16;
    return __builtin_bit_cast(float, u);
}

// ---------------- counting sort ----------------
__global__ void k_hist(const int* __restrict__ idx, int n, int limit,
                       int* __restrict__ hist) {
    int i = blockIdx.x * blockDim.x + threadIdx.x;
    if (i < n) { int v = idx[i]; if (v < limit) atomicAdd(&hist[v], 1); }
}

__global__ __launch_bounds__(1024) void k_scan(const int* __restrict__ hist,
                                               int* __restrict__ cursor,
                                               int* __restrict__ total) {
    __shared__ int s[1024];
    const int tid = threadIdx.x;
    const int per = (Nn + 1023) / 1024;
    int start = tid * per, end = min(start + per, Nn);
    int sum = 0;
    for (int i = start; i < end; ++i) sum += hist[i];
    s[tid] = sum;
    __syncthreads();
    for (int off = 1; off < 1024; off <<= 1) {
        int v = (tid >= off) ? s[tid - off] : 0;
        __syncthreads();
        s[tid] += v;
        __syncthreads();
    }
    int base = s[tid] - sum;
    for (int i = start; i < end; ++i) {
        cursor[i] = base;
        base += hist[i];
    }
    if (tid == 1023 && total) *total = s[1023];
}

// scatter with payloads: outA[p] = valA ? valA[i] : i ; optional outB[p] = valB[i]
// After this kernel, cursor[v] == row_end[v]; row_beg = cursor[v] - hist[v].
__global__ void k_scatter2(const int* __restrict__ key, const int* __restrict__ valA,
                           const int* __restrict__ valB, int n, int limit,
                           int* __restrict__ cursor,
                           int* __restrict__ outA, int* __restrict__ outB) {
    int i = blockIdx.x * blockDim.x + threadIdx.x;
    if (i < n) {
        int v = key[i];
        if (v < limit) {
            int p = atomicAdd(&cursor[v], 1);
            outA[p] = valA ? valA[i] : i;
            if (outB) outB[p] = valB[i];
        }
    }
}

// ---------------- fused per-layer weight transpose to bf16 ----------------
__global__ void k_wtall(const float* __restrict__ We1a, const float* __restrict__ We1b,
                        const float* __restrict__ We2a, const float* __restrict__ We2b,
                        const float* __restrict__ Wna,  const float* __restrict__ Wnb,
                        unsigned short* __restrict__ base) {
    int idx = blockIdx.x * blockDim.x + threadIdx.x;
    if (idx >= 135168) return;
    const float* src; int K, Kp, loc;
    if (idx < 16384)       { src = We1a;             K = 128; Kp = 128; loc = idx; }
    else if (idx < 20480)  { src = We1a + 128 * 128; K = 6;   Kp = 32;  loc = idx - 16384; }
    else if (idx < 36864)  { src = We1b;             K = 128; Kp = 128; loc = idx - 20480; }
    else if (idx < 69632)  { src = We2a;             K = 256; Kp = 256; loc = idx - 36864; }
    else if (idx < 86016)  { src = We2b;             K = 128; Kp = 128; loc = idx - 69632; }
    else if (idx < 118784) { src = Wna;              K = 256; Kp = 256; loc = idx - 86016; }
    else                   { src = Wnb;              K = 128; Kp = 128; loc = idx - 118784; }
    int n = loc / Kp, k = loc - n * Kp;
    base[idx] = (k < K) ? f2bf(src[(size_t)k * 128 + n]) : (unsigned short)0;
}

// ---------------- x -> bf16 h0 ----------------
__global__ void k_h0(const float* __restrict__ x, unsigned short* __restrict__ hb) {
    int idx = blockIdx.x * blockDim.x + threadIdx.x;
    if (idx < Nn * Hh) hb[idx] = f2bf(x[idx]);
}

// ---------------- GEMM building blocks ----------------
__device__ __forceinline__ void zacc(f32x4 acc[4][2]) {
#pragma unroll
    for (int rt = 0; rt < 4; ++rt)
#pragma unroll
        for (int ct = 0; ct < 2; ++ct)
            acc[rt][ct] = (f32x4){0.f, 0.f, 0.f, 0.f};
}

template<int KK, int SA, int KP>
__device__ __forceinline__ void gemm64(const unsigned short* A,
                                       const unsigned short* __restrict__ Wt,
                                       int k_off, f32x4 acc[4][2]) {
    const int tid = threadIdx.x;
    const int lane = tid & 63;
    const int nb = (tid >> 6) * 32;
    const int rA = lane & 15;
    const int kg = lane >> 4;
#pragma unroll
    for (int ks = 0; ks < KK / 32; ++ks) {
        const int ka = ks * 32 + kg * 8;
        const int kb = k_off + ka;
        bf16x8 b0 = *(const bf16x8*)&Wt[(size_t)(nb + rA) * KP + kb];
        bf16x8 b1 = *(const bf16x8*)&Wt[(size_t)(nb + 16 + rA) * KP + kb];
#pragma unroll
        for (int rt = 0; rt < 4; ++rt) {
            bf16x8 a = *(const bf16x8*)&A[(rt * 16 + rA) * SA + ka];
            acc[rt][0] = __builtin_amdgcn_mfma_f32_16x16x32_bf16(a, b0, acc[rt][0], 0, 0, 0);
            acc[rt][1] = __builtin_amdgcn_mfma_f32_16x16x32_bf16(a, b1, acc[rt][1], 0, 0, 0);
        }
    }
}

__device__ __forceinline__ void store_acc(const f32x4 acc[4][2], unsigned short* out,
                                          int n0, int nmax) {
    const int tid = threadIdx.x;
    const int lane = tid & 63;
    const int nb = (tid >> 6) * 32;
    const int rA = lane & 15, kg = lane >> 4;
#pragma unroll
    for (int rt = 0; rt < 4; ++rt)
#pragma unroll
        for (int ct = 0; ct < 2; ++ct) {
            int col = nb + ct * 16 + rA;
#pragma unroll
            for (int i = 0; i < 4; ++i) {
                int n = n0 + rt * 16 + kg * 4 + i;
                if (n < nmax) out[(size_t)n * 128 + col] = f2bf(acc[rt][ct][i]);
            }
        }
}

// ---------------- k_pre: P1 = h*Wq1, Z1 = h*We2a[0:128], P2 = rbf*Wp2 ----------------
__global__ __launch_bounds__(256) void k_pre(
    const unsigned short* __restrict__ hb, const float* __restrict__ rbf,
    const unsigned short* __restrict__ wb,
    unsigned short* __restrict__ P1, unsigned short* __restrict__ Z1,
    unsigned short* __restrict__ P2)
{
    __shared__ unsigned short L[64 * 136];
    const int m0 = blockIdx.x * 64;
    const int tid = threadIdx.x;
    const unsigned short* Wq1t = wb;
    const unsigned short* Wp2t = wb + 16384;
    const unsigned short* We2at = wb + 36864;
    for (int i = tid; i < 64 * 16; i += 256) {
        int row = i >> 4, ch = i & 15;
        int n = min(m0 + row, Nn - 1);
        *(uint4*)&L[row * 136 + ch * 8] = *(const uint4*)&hb[(size_t)n * 128 + ch * 8];
    }
    __syncthreads();
    f32x4 acc[4][2];
    zacc(acc);
    gemm64<128, 136, 128>(L, Wq1t, 0, acc);
    store_acc(acc, P1, m0, Nn);
    zacc(acc);
    gemm64<128, 136, 256>(L, We2at, 0, acc);
    store_acc(acc, Z1, m0, Nn);
    __syncthreads();
    for (int i = tid; i < 64 * 32; i += 256) {
        int row = i >> 5, c = i & 31;
        int n = min(m0 + row, Nn - 1);
        float v = (c < 6) ? rbf[(size_t)n * 6 + c] : 0.f;
        L[row * 136 + c] = f2bf(v);
    }
    __syncthreads();
    zacc(acc);
    gemm64<32, 136, 32>(L, Wp2t, 0, acc);
    store_acc(acc, P2, m0, Nn);
}

// ---------------- k_quadagg: CSR owner-computes quad reduction (ZERO atomics) --------
// thread = (node nd, col-chunk c0); loops the node's sorted quad list, accumulates
// relu(P1[l] + P2[n] + [cbf|sbf]*W34 + b) in registers, ONE bf16 store.
__global__ __launch_bounds__(256) void k_quadagg(
    const unsigned short* __restrict__ P1, const unsigned short* __restrict__ P2,
    const float* __restrict__ cbf, const float* __restrict__ sbf,
    const int* __restrict__ qlist, const int* __restrict__ lq,
    const int* __restrict__ rowend, const int* __restrict__ rowcnt,
    const float* __restrict__ We1a_raw, const float* __restrict__ b_e1a,
    unsigned short* __restrict__ Rb)
{
    __shared__ float W34[12 * 128];
    __shared__ float bia[128];
    const int tid = threadIdx.x;
    for (int i = tid; i < 12 * 128; i += 256) W34[i] = We1a_raw[134 * 128 + i];
    if (tid < 128) bia[tid] = b_e1a[tid];
    __syncthreads();
    const int nd = tid >> 4;
    const int c0 = (tid & 15) * 8;
    const int n = blockIdx.x * 16 + nd;
    const int end = rowend[n];
    const int beg = end - rowcnt[n];
    float base[8];
    {
        uint4 p2v = *(const uint4*)&P2[(size_t)n * 128 + c0];
        const unsigned short* pp = (const unsigned short*)&p2v;
#pragma unroll
        for (int k = 0; k < 8; ++k) base[k] = bia[c0 + k] + bf2f(pp[k]);
    }
    float acc[8];
#pragma unroll
    for (int k = 0; k < 8; ++k) acc[k] = 0.f;
    for (int e = beg; e < end; ++e) {
        int q = qlist[e];
        int l = lq[e];
        uint4 a = *(const uint4*)&P1[(size_t)l * 128 + c0];
        float2 c01 = *(const float2*)&cbf[(size_t)q * 6];
        float2 c23 = *(const float2*)&cbf[(size_t)q * 6 + 2];
        float2 c45 = *(const float2*)&cbf[(size_t)q * 6 + 4];
        float2 s01 = *(const float2*)&sbf[(size_t)q * 6];
        float2 s23 = *(const float2*)&sbf[(size_t)q * 6 + 2];
        float2 s45 = *(const float2*)&sbf[(size_t)q * 6 + 4];
        float qv[12] = {c01.x, c01.y, c23.x, c23.y, c45.x, c45.y,
                        s01.x, s01.y, s23.x, s23.y, s45.x, s45.y};
        const unsigned short* ap = (const unsigned short*)&a;
        float t[8];
#pragma unroll
        for (int k = 0; k < 8; ++k) t[k] = base[k] + bf2f(ap[k]);
#pragma unroll
        for (int kk = 0; kk < 12; ++kk) {
            float q_ = qv[kk];
#pragma unroll
            for (int k = 0; k < 8; ++k)
                t[k] = fmaf(q_, W34[kk * 128 + c0 + k], t[k]);
        }
#pragma unroll
        for (int k = 0; k < 8; ++k) acc[k] += fmaxf(t[k], 0.f);
    }
    unsigned short ov[8];
#pragma unroll
    for (int k = 0; k < 8; ++k) ov[k] = f2bf(acc[k]);
    *(uint4*)&Rb[(size_t)n * 128 + c0] = *(uint4*)ov;
}

// ---------------- k_edgeagg: CSR owner-computes edge reduction (ZERO atomics) --------
// Rb[n] = sum over edges with dst==n of relu(Z1[src] + Z2[n] + b_e2a); bf16 store.
__global__ __launch_bounds__(256) void k_edgeagg(
    const unsigned short* __restrict__ Z1, const unsigned short* __restrict__ Z2,
    const int* __restrict__ srcs,
    const int* __restrict__ rowend, const int* __restrict__ rowcnt,
    const float* __restrict__ b_e2a,
    unsigned short* __restrict__ Rb)
{
    const int tid = threadIdx.x;
    const int nd = tid >> 4;
    const int c0 = (tid & 15) * 8;
    const int n = blockIdx.x * 16 + nd;
    const int end = rowend[n];
    const int beg = end - rowcnt[n];
    float z2b[8];
    {
        uint4 zv = *(const uint4*)&Z2[(size_t)n * 128 + c0];
        const unsigned short* zp = (const unsigned short*)&zv;
        float4 b0 = *(const float4*)&b_e2a[c0];
        float4 b1 = *(const float4*)&b_e2a[c0 + 4];
        z2b[0] = b0.x + bf2f(zp[0]); z2b[1] = b0.y + bf2f(zp[1]);
        z2b[2] = b0.z + bf2f(zp[2]); z2b[3] = b0.w + bf2f(zp[3]);
        z2b[4] = b1.x + bf2f(zp[4]); z2b[5] = b1.y + bf2f(zp[5]);
        z2b[6] = b1.z + bf2f(zp[6]); z2b[7] = b1.w + bf2f(zp[7]);
    }
    float acc[8];
#pragma unroll
    for (int k = 0; k < 8; ++k) acc[k] = 0.f;
    int e = beg;
    for (; e + 2 <= end; e += 2) {           // 2-way ILP on the gather
        int s0 = srcs[e], s1 = srcs[e + 1];
        uint4 a0 = *(const uint4*)&Z1[(size_t)s0 * 128 + c0];
        uint4 a1 = *(const uint4*)&Z1[(size_t)s1 * 128 + c0];
        const unsigned short* p0 = (const unsigned short*)&a0;
        const unsigned short* p1 = (const unsigned short*)&a1;
#pragma unroll
        for (int k = 0; k < 8; ++k) acc[k] += fmaxf(z2b[k] + bf2f(p0[k]), 0.f);
#pragma unroll
        for (int k = 0; k < 8; ++k) acc[k] += fmaxf(z2b[k] + bf2f(p1[k]), 0.f);
    }
    if (e < end) {
        int s0 = srcs[e];
        uint4 a0 = *(const uint4*)&Z1[(size_t)s0 * 128 + c0];
        const unsigned short* p0 = (const unsigned short*)&a0;
#pragma unroll
        for (int k = 0; k < 8; ++k) acc[k] += fmaxf(z2b[k] + bf2f(p0[k]), 0.f);
    }
    unsigned short ov[8];
#pragma unroll
    for (int k = 0; k < 8; ++k) ov[k] = f2bf(acc[k]);
    *(uint4*)&Rb[(size_t)n * 128 + c0] = *(uint4*)ov;
}

// ---------------- k_agg2z: T = Rq*We1b + cntq*b_e1b ; Z2 = T*We2a[128:256] ----------------
__global__ __launch_bounds__(256) void k_agg2z(
    const unsigned short* __restrict__ Rb, const int* __restrict__ cntq,
    const unsigned short* __restrict__ wb, const float* __restrict__ b_e1b,
    unsigned short* __restrict__ Z2)
{
    __shared__ unsigned short L[64 * 136];
    __shared__ int rc[64];
    const int m0 = blockIdx.x * 64;
    const int tid = threadIdx.x;
    const unsigned short* We1bt = wb + 20480;
    const unsigned short* We2at = wb + 36864;
    if (tid < 64) rc[tid] = (m0 + tid < Nn) ? cntq[m0 + tid] : 0;
    for (int i = tid; i < 64 * 16; i += 256) {
        int row = i >> 4, ch = i & 15;
        int n = min(m0 + row, Nn - 1);
        *(uint4*)&L[row * 136 + ch * 8] = *(const uint4*)&Rb[(size_t)n * 128 + ch * 8];
    }
    __syncthreads();
    f32x4 acc[4][2];
    zacc(acc);
    gemm64<128, 136, 128>(L, We1bt, 0, acc);
    __syncthreads();
    {
        const int lane = tid & 63;
        const int nb = (tid >> 6) * 32;
        const int rA = lane & 15, kg = lane >> 4;
#pragma unroll
        for (int rt = 0; rt < 4; ++rt)
#pragma unroll
            for (int ct = 0; ct < 2; ++ct) {
                int col = nb + ct * 16 + rA;
                float bias = b_e1b[col];
#pragma unroll
                for (int i = 0; i < 4; ++i) {
                    int row = rt * 16 + kg * 4 + i;
                    L[row * 136 + col] = f2bf(acc[rt][ct][i] + (float)rc[row] * bias);
                }
            }
    }
    __syncthreads();
    zacc(acc);
    gemm64<128, 136, 256>(L, We2at, 128, acc);
    store_acc(acc, Z2, m0, Nn);
}

// ---------------- k_nodeNew: U=Re*We2b+deg*b2; V=U*Wna[128:]+h*Wna[:128]; h'=ReLU(V+b)*Wnb+b ----------------
__global__ __launch_bounds__(256) void k_nodeNew(
    const unsigned short* __restrict__ Rb, const int* __restrict__ deg,
    const unsigned short* __restrict__ hb,
    const unsigned short* __restrict__ wb,
    const float* __restrict__ b_e2b, const float* __restrict__ b_na,
    const float* __restrict__ b_nb,
    unsigned short* __restrict__ hnew)
{
    __shared__ unsigned short L[64 * 136];
    __shared__ int rc[64];
    const int m0 = blockIdx.x * 64;
    const int tid = threadIdx.x;
    const unsigned short* We2bt = wb + 69632;
    const unsigned short* Wnat  = wb + 86016;
    const unsigned short* Wnbt  = wb + 118784;
    const int lane = tid & 63;
    const int nb = (tid >> 6) * 32;
    const int rA = lane & 15, kg = lane >> 4;
    if (tid < 64) rc[tid] = (m0 + tid < Nn) ? deg[m0 + tid] : 0;
    for (int i = tid; i < 64 * 16; i += 256) {
        int row = i >> 4, ch = i & 15;
        int n = min(m0 + row, Nn - 1);
        *(uint4*)&L[row * 136 + ch * 8] = *(const uint4*)&Rb[(size_t)n * 128 + ch * 8];
    }
    __syncthreads();
    f32x4 acc[4][2];
    zacc(acc);
    gemm64<128, 136, 128>(L, We2bt, 0, acc);     // U = Re*We2b
    __syncthreads();
#pragma unroll
    for (int rt = 0; rt < 4; ++rt)
#pragma unroll
        for (int ct = 0; ct < 2; ++ct) {
            int col = nb + ct * 16 + rA;
            float bias = b_e2b[col];
#pragma unroll
            for (int i = 0; i < 4; ++i) {
                int row = rt * 16 + kg * 4 + i;
                L[row * 136 + col] = f2bf(acc[rt][ct][i] + (float)rc[row] * bias);
            }
        }
    __syncthreads();
    f32x4 acc2[4][2];
    zacc(acc2);
    gemm64<128, 136, 256>(L, Wnat, 128, acc2);   // V = U*Wbot_n
    __syncthreads();
    for (int i = tid; i < 64 * 16; i += 256) {
        int row = i >> 4, ch = i & 15;
        int n = min(m0 + row, Nn - 1);
        *(uint4*)&L[row * 136 + ch * 8] = *(const uint4*)&hb[(size_t)n * 128 + ch * 8];
    }
    __syncthreads();
    gemm64<128, 136, 256>(L, Wnat, 0, acc2);     // V += h*Wtop_n
    __syncthreads();
#pragma unroll
    for (int rt = 0; rt < 4; ++rt)
#pragma unroll
        for (int ct = 0; ct < 2; ++ct) {
            int col = nb + ct * 16 + rA;
            float bias = b_na[col];
#pragma unroll
            for (int i = 0; i < 4; ++i) {
                int row = rt * 16 + kg * 4 + i;
                L[row * 136 + col] = f2bf(fmaxf(acc2[rt][ct][i] + bias, 0.f));
            }
        }
    __syncthreads();
    zacc(acc);
    gemm64<128, 136, 128>(L, Wnbt, 0, acc);      // hidden*Wnb
#pragma unroll
    for (int rt = 0; rt < 4; ++rt)
#pragma unroll
        for (int ct = 0; ct < 2; ++ct) {
            int col = nb + ct * 16 + rA;
            float bias = b_nb[col];
#pragma unroll
            for (int i = 0; i < 4; ++i) {
                int n = m0 + rt * 16 + kg * 4 + i;
                if (n < Nn)
                    hnew[(size_t)n * 128 + col] = f2bf(acc[rt][ct][i] + bias);
            }
        }
}

// ---------------- global mean pool: run-length segmented reduction ----------------
__global__ __launch_bounds__(256) void k_pool(const unsigned short* __restrict__ hb,
                                              const int* __restrict__ batch,
                                              float* __restrict__ pooled,
                                              float* __restrict__ cntg) {
    __shared__ int bseg[200];
    constexpr int CH = 196;
    const int start = blockIdx.x * CH;
    const int end = min(start + CH, Nn);
    if (start >= end) return;
    const int tid = threadIdx.x;
    for (int i = tid; i < end - start; i += 256) bseg[i] = batch[start + i];
    __syncthreads();
    const int j = tid & 127;
    const int rh = tid >> 7;
    float acc = 0.f, cacc = 0.f;
    int cur = -1;
    for (int n = start + rh; n < end; n += 2) {
        int g = bseg[n - start];
        if (g != cur) {
            if (cur >= 0) {
                atomicAdd(&pooled[cur * Hh + j], acc);
                if (j == 0) atomicAdd(&cntg[cur], cacc);
            }
            cur = g; acc = 0.f; cacc = 0.f;
        }
        acc += bf2f(hb[(size_t)n * Hh + j]);
        cacc += 1.f;
    }
    if (cur >= 0) {
        atomicAdd(&pooled[cur * Hh + j], acc);
        if (j == 0) atomicAdd(&cntg[cur], cacc);
    }
}

// ---------------- final per-graph MLP ----------------
__global__ __launch_bounds__(128) void k_final(
    const float* __restrict__ pooled, const float* __restrict__ cntg,
    const float* __restrict__ Woa, const float* __restrict__ boa,
    const float* __restrict__ Wob, const float* __restrict__ bob,
    float* __restrict__ out)
{
    __shared__ float p[128];
    __shared__ float t[128];
    __shared__ float red[128];
    const int g = blockIdx.x;
    const int j = threadIdx.x;
    float c = fmaxf(cntg[g], 1.f);
    p[j] = fmaxf(pooled[g * Hh + j] / c, 0.f);
    __syncthreads();
    float acc = boa[j];
    for (int d = 0; d < Hh; ++d) acc = fmaf(p[d], Woa[d * Hh + j], acc);
    t[j] = fmaxf(acc, 0.f);
    __syncthreads();
    red[j] = t[j] * Wob[j];
    __syncthreads();
    for (int s = 64; s > 0; s >>= 1) {
        if (j < s) red[j] += red[j + s];
        __syncthreads();
    }
    if (j == 0) out[g] = red[0] + bob[0];
}

extern "C" void kernel_launch(void* const* d_in, const int* in_sizes, int n_in,
                              void* d_out, int out_size, void* d_ws, size_t ws_size,
                              hipStream_t stream) {
    const float* x     = (const float*)d_in[0];
    const float* rbf   = (const float*)d_in[1];
    const float* cbf   = (const float*)d_in[2];
    const float* sbf   = (const float*)d_in[3];
    const int*   eidx  = (const int*)d_in[4];
    const int*   l_idx = (const int*)d_in[5];
    const int*   k_idx = (const int*)d_in[6];
    const int*   batch = (const int*)d_in[7];
    const float* W_e1a = (const float*)d_in[8];
    const float* b_e1a = (const float*)d_in[9];
    const float* W_e1b = (const float*)d_in[10];
    const float* b_e1b = (const float*)d_in[11];
    const float* W_e2a = (const float*)d_in[12];
    const float* b_e2a = (const float*)d_in[13];
    const float* W_e2b = (const float*)d_in[14];
    const float* b_e2b = (const float*)d_in[15];
    const float* W_na  = (const float*)d_in[16];
    const float* b_na  = (const float*)d_in[17];
    const float* W_nb  = (const float*)d_in[18];
    const float* b_nb  = (const float*)d_in[19];
    const float* W_oa  = (const float*)d_in[20];
    const float* b_oa  = (const float*)d_in[21];
    const float* W_ob  = (const float*)d_in[22];
    const float* b_ob  = (const float*)d_in[23];

    const int* src = eidx;
    const int* dst = eidx + Ee;

    const size_t NHb = (size_t)Nn * Hh * sizeof(unsigned short);
    char* w = (char*)d_ws;
    unsigned short* hb0 = (unsigned short*)w; w += NHb;
    unsigned short* hb1 = (unsigned short*)w; w += NHb;
    unsigned short* P1  = (unsigned short*)w; w += NHb;
    unsigned short* P2  = (unsigned short*)w; w += NHb;
    unsigned short* Z1  = (unsigned short*)w; w += NHb;
    unsigned short* Z2  = (unsigned short*)w; w += NHb;
    unsigned short* Rb  = (unsigned short*)w; w += NHb;   // shared Rq / Re (bf16)
    float* pooled = (float*)w; w += (size_t)Gg * Hh * sizeof(float);
    float* cntg   = (float*)w; w += (size_t)Gg * sizeof(float);
    int*   qlist  = (int*)w;   w += (size_t)Qq * sizeof(int);
    int*   lq     = (int*)w;   w += (size_t)Qq * sizeof(int);
    int*   srcs_e = (int*)w;   w += (size_t)Ee * sizeof(int);
    int*   hist_e = (int*)w;   w += (size_t)Nn * sizeof(int);
    int*   hist_q = (int*)w;   w += (size_t)Nn * sizeof(int);
    int*   cur_e  = (int*)w;   w += (size_t)Nn * sizeof(int);
    int*   cur_q  = (int*)w;   w += (size_t)Nn * sizeof(int);
    int*   qcnt   = (int*)w;   w += 16;
    unsigned short* wbuf = (unsigned short*)w;            // 3 x 135168 bf16

    const size_t LSTRIDE = 135168;

    // --- counting sort: edges by dst; payload = src value (CSR-ready) ---
    hipMemsetAsync(hist_e, 0, Nn * sizeof(int), stream);
    k_hist<<<(Ee + 255) / 256, 256, 0, stream>>>(dst, Ee, Nn, hist_e);
    k_scan<<<1, 1024, 0, stream>>>(hist_e, cur_e, (int*)nullptr);
    k_scatter2<<<(Ee + 255) / 256, 256, 0, stream>>>(dst, src, (const int*)nullptr,
        Ee, Nn, cur_e, srcs_e, (int*)nullptr);
    // --- counting sort: quads by k_idx (compaction k<Nn); payloads = (q, l_idx[q]) ---
    hipMemsetAsync(hist_q, 0, Nn * sizeof(int), stream);
    k_hist<<<(Qq + 255) / 256, 256, 0, stream>>>(k_idx, Qq, Nn, hist_q);
    k_scan<<<1, 1024, 0, stream>>>(hist_q, cur_q, qcnt);
    k_scatter2<<<(Qq + 255) / 256, 256, 0, stream>>>(k_idx, (const int*)nullptr, l_idx,
        Qq, Nn, cur_q, qlist, lq);

    k_h0<<<(Nn * Hh + 255) / 256, 256, 0, stream>>>(x, hb0);

    for (int p = 0; p < 3; ++p) {
        k_wtall<<<(135168 + 255) / 256, 256, 0, stream>>>(
            W_e1a + (size_t)p * 146 * 128, W_e1b + (size_t)p * 128 * 128,
            W_e2a + (size_t)p * 256 * 128, W_e2b + (size_t)p * 128 * 128,
            W_na  + (size_t)p * 256 * 128, W_nb  + (size_t)p * 128 * 128,
            wbuf + p * LSTRIDE);
    }

    unsigned short* bufs[2] = { hb0, hb1 };
    int cur = 0;
    for (int p = 0; p < 3; ++p) {
        const unsigned short* wb = wbuf + p * LSTRIDE;
        k_pre<<<NB64, 256, 0, stream>>>(bufs[cur], rbf, wb, P1, Z1, P2);
        k_quadagg<<<Nn / 16, 256, 0, stream>>>(P1, P2, cbf, sbf, qlist, lq,
            cur_q, hist_q, W_e1a + (size_t)p * 146 * 128, b_e1a + (size_t)p * 128, Rb);
        k_agg2z<<<NB64, 256, 0, stream>>>(Rb, hist_q, wb, b_e1b + (size_t)p * 128, Z2);
        k_edgeagg<<<Nn / 16, 256, 0, stream>>>(Z1, Z2, srcs_e, cur_e, hist_e,
            b_e2a + (size_t)p * 128, Rb);
        k_nodeNew<<<NB64, 256, 0, stream>>>(Rb, hist_e, bufs[cur], wb,
            b_e2b + (size_t)p * 128, b_na + (size_t)p * 128, b_nb + (size_t)p * 128,
            bufs[cur ^ 1]);
        cur ^= 1;
    }
    hipMemsetAsync(pooled, 0, (size_t)Gg * Hh * sizeof(float), stream);
    hipMemsetAsync(cntg, 0, (size_t)Gg * sizeof(float), stream);
    k_pool<<<(Nn + 195) / 196, 256, 0, stream>>>(bufs[cur], batch, pooled, cntg);
    k_final<<<Gg, 128, 0, stream>>>(pooled, cntg, W_oa, b_oa, W_ob, b_ob, (float*)d_out);
}

// Round 8
// 572.229 us; speedup vs baseline: 5.1200x; 1.2740x over previous
//
#include <hip/hip_runtime.h>

constexpr int Nn = 50000;
constexpr int Ee = 800000;
constexpr int Qq = 2000000;
constexpr int Gg = 64;
constexpr int Hh = 128;
constexpr int NB64 = (Nn + 63) / 64;
constexpr int NSCB = (Nn + 1023) / 1024;   // 49 scan blocks

typedef short bf16x8 __attribute__((ext_vector_type(8)));
typedef float f32x4  __attribute__((ext_vector_type(4)));

__device__ __forceinline__ unsigned short f2bf(float f) {
    unsigned u = __builtin_bit_cast(unsigned, f);
    u += 0x7FFFu + ((u >> 16) & 1u);
    return (unsigned short)(u >> 16);
}
__device__ __forceinline__ float bf2f(unsigned short s) {
    unsigned u = ((unsigned)s) << 16;
    return __builtin_bit_cast(float, u);
}

// ---------------- counting sort: histogram ----------------
__global__ void k_hist(const int* __restrict__ idx, int n, int limit,
                       int* __restrict__ hist) {
    int i = blockIdx.x * blockDim.x + threadIdx.x;
    if (i < n) { int v = idx[i]; if (v < limit) atomicAdd(&hist[v], 1); }
}

// ---------------- hierarchical exclusive scan over Nn bins (3 kernels) ----------------
__global__ __launch_bounds__(1024) void k_scanA(const int* __restrict__ hist,
                                                int* __restrict__ cursor,
                                                int* __restrict__ bsum) {
    __shared__ int s[1024];
    const int tid = threadIdx.x;
    int i = blockIdx.x * 1024 + tid;
    int v = (i < Nn) ? hist[i] : 0;
    s[tid] = v;
    __syncthreads();
    for (int off = 1; off < 1024; off <<= 1) {
        int t = (tid >= off) ? s[tid - off] : 0;
        __syncthreads();
        s[tid] += t;
        __syncthreads();
    }
    if (i < Nn) cursor[i] = s[tid] - v;
    if (tid == 1023) bsum[blockIdx.x] = s[1023];
}
__global__ void k_scanB(int* __restrict__ bsum) {
    __shared__ int s[64];
    const int tid = threadIdx.x;
    int v = (tid < NSCB) ? bsum[tid] : 0;
    s[tid] = v;
    __syncthreads();
    for (int off = 1; off < 64; off <<= 1) {
        int t = (tid >= off) ? s[tid - off] : 0;
        __syncthreads();
        s[tid] += t;
        __syncthreads();
    }
    if (tid < NSCB) bsum[tid] = s[tid] - v;   // exclusive block offsets
}
__global__ __launch_bounds__(1024) void k_scanC(int* __restrict__ cursor,
                                                const int* __restrict__ bsum) {
    int i = blockIdx.x * 1024 + threadIdx.x;
    if (i < Nn) cursor[i] += bsum[blockIdx.x];
}

// ---------------- scatter: edges (payload = src value) ----------------
__global__ void k_scatter_e(const int* __restrict__ dst, const int* __restrict__ src,
                            int* __restrict__ cursor, int* __restrict__ srcs) {
    int i = blockIdx.x * blockDim.x + threadIdx.x;
    if (i < Ee) {
        int v = dst[i];
        int p = atomicAdd(&cursor[v], 1);
        srcs[p] = src[i];
    }
}

// ---------------- scatter: quads (payload = l_idx + 12 bf16 feat, CSR-ordered) -------
__global__ void k_scatter_q(const int* __restrict__ k_idx, const int* __restrict__ l_idx,
                            const float* __restrict__ cbf, const float* __restrict__ sbf,
                            int* __restrict__ cursor,
                            int* __restrict__ lq, unsigned short* __restrict__ qfeat) {
    int i = blockIdx.x * blockDim.x + threadIdx.x;
    if (i >= Qq) return;
    int v = k_idx[i];
    if (v >= Nn) return;
    int p = atomicAdd(&cursor[v], 1);
    lq[p] = l_idx[i];
    unsigned short f[12];
#pragma unroll
    for (int k = 0; k < 6; ++k) f[k] = f2bf(cbf[(size_t)i * 6 + k]);
#pragma unroll
    for (int k = 0; k < 6; ++k) f[6 + k] = f2bf(sbf[(size_t)i * 6 + k]);
    *(uint2*)&qfeat[(size_t)p * 12]     = *(uint2*)&f[0];
    *(uint2*)&qfeat[(size_t)p * 12 + 4] = *(uint2*)&f[4];
    *(uint2*)&qfeat[(size_t)p * 12 + 8] = *(uint2*)&f[8];
}

// ---------------- fused per-layer weight transpose to bf16 (all 3 layers, 2-D grid) --
__global__ void k_wtall(const float* __restrict__ We1a0, const float* __restrict__ We1b0,
                        const float* __restrict__ We2a0, const float* __restrict__ We2b0,
                        const float* __restrict__ Wna0,  const float* __restrict__ Wnb0,
                        unsigned short* __restrict__ wbuf) {
    int idx = blockIdx.x * blockDim.x + threadIdx.x;
    if (idx >= 135168) return;
    const int p = blockIdx.y;
    const float* We1a = We1a0 + (size_t)p * 146 * 128;
    const float* We1b = We1b0 + (size_t)p * 128 * 128;
    const float* We2a = We2a0 + (size_t)p * 256 * 128;
    const float* We2b = We2b0 + (size_t)p * 128 * 128;
    const float* Wna  = Wna0  + (size_t)p * 256 * 128;
    const float* Wnb  = Wnb0  + (size_t)p * 128 * 128;
    unsigned short* base = wbuf + (size_t)p * 135168;
    const float* src; int K, Kp, loc;
    if (idx < 16384)       { src = We1a;             K = 128; Kp = 128; loc = idx; }
    else if (idx < 20480)  { src = We1a + 128 * 128; K = 6;   Kp = 32;  loc = idx - 16384; }
    else if (idx < 36864)  { src = We1b;             K = 128; Kp = 128; loc = idx - 20480; }
    else if (idx < 69632)  { src = We2a;             K = 256; Kp = 256; loc = idx - 36864; }
    else if (idx < 86016)  { src = We2b;             K = 128; Kp = 128; loc = idx - 69632; }
    else if (idx < 118784) { src = Wna;              K = 256; Kp = 256; loc = idx - 86016; }
    else                   { src = Wnb;              K = 128; Kp = 128; loc = idx - 118784; }
    int n = loc / Kp, k = loc - n * Kp;
    base[idx] = (k < K) ? f2bf(src[(size_t)k * 128 + n]) : (unsigned short)0;
}

// ---------------- x -> bf16 h0 ----------------
__global__ void k_h0(const float* __restrict__ x, unsigned short* __restrict__ hb) {
    int idx = blockIdx.x * blockDim.x + threadIdx.x;
    if (idx < Nn * Hh) hb[idx] = f2bf(x[idx]);
}

// ---------------- GEMM building blocks ----------------
__device__ __forceinline__ void zacc(f32x4 acc[4][2]) {
#pragma unroll
    for (int rt = 0; rt < 4; ++rt)
#pragma unroll
        for (int ct = 0; ct < 2; ++ct)
            acc[rt][ct] = (f32x4){0.f, 0.f, 0.f, 0.f};
}

template<int KK, int SA, int KP>
__device__ __forceinline__ void gemm64(const unsigned short* A,
                                       const unsigned short* __restrict__ Wt,
                                       int k_off, f32x4 acc[4][2]) {
    const int tid = threadIdx.x;
    const int lane = tid & 63;
    const int nb = (tid >> 6) * 32;
    const int rA = lane & 15;
    const int kg = lane >> 4;
#pragma unroll
    for (int ks = 0; ks < KK / 32; ++ks) {
        const int ka = ks * 32 + kg * 8;
        const int kb = k_off + ka;
        bf16x8 b0 = *(const bf16x8*)&Wt[(size_t)(nb + rA) * KP + kb];
        bf16x8 b1 = *(const bf16x8*)&Wt[(size_t)(nb + 16 + rA) * KP + kb];
#pragma unroll
        for (int rt = 0; rt < 4; ++rt) {
            bf16x8 a = *(const bf16x8*)&A[(rt * 16 + rA) * SA + ka];
            acc[rt][0] = __builtin_amdgcn_mfma_f32_16x16x32_bf16(a, b0, acc[rt][0], 0, 0, 0);
            acc[rt][1] = __builtin_amdgcn_mfma_f32_16x16x32_bf16(a, b1, acc[rt][1], 0, 0, 0);
        }
    }
}

__device__ __forceinline__ void store_acc(const f32x4 acc[4][2], unsigned short* out,
                                          int n0, int nmax) {
    const int tid = threadIdx.x;
    const int lane = tid & 63;
    const int nb = (tid >> 6) * 32;
    const int rA = lane & 15, kg = lane >> 4;
#pragma unroll
    for (int rt = 0; rt < 4; ++rt)
#pragma unroll
        for (int ct = 0; ct < 2; ++ct) {
            int col = nb + ct * 16 + rA;
#pragma unroll
            for (int i = 0; i < 4; ++i) {
                int n = n0 + rt * 16 + kg * 4 + i;
                if (n < nmax) out[(size_t)n * 128 + col] = f2bf(acc[rt][ct][i]);
            }
        }
}

// ---------------- k_pre: P1 = h*Wq1, Z1 = h*We2a[0:128], P2 = rbf*Wp2 ----------------
__global__ __launch_bounds__(256) void k_pre(
    const unsigned short* __restrict__ hb, const float* __restrict__ rbf,
    const unsigned short* __restrict__ wb,
    unsigned short* __restrict__ P1, unsigned short* __restrict__ Z1,
    unsigned short* __restrict__ P2)
{
    __shared__ unsigned short L[64 * 136];
    const int m0 = blockIdx.x * 64;
    const int tid = threadIdx.x;
    const unsigned short* Wq1t = wb;
    const unsigned short* Wp2t = wb + 16384;
    const unsigned short* We2at = wb + 36864;
    for (int i = tid; i < 64 * 16; i += 256) {
        int row = i >> 4, ch = i & 15;
        int n = min(m0 + row, Nn - 1);
        *(uint4*)&L[row * 136 + ch * 8] = *(const uint4*)&hb[(size_t)n * 128 + ch * 8];
    }
    __syncthreads();
    f32x4 acc[4][2];
    zacc(acc);
    gemm64<128, 136, 128>(L, Wq1t, 0, acc);
    store_acc(acc, P1, m0, Nn);
    zacc(acc);
    gemm64<128, 136, 256>(L, We2at, 0, acc);
    store_acc(acc, Z1, m0, Nn);
    __syncthreads();
    for (int i = tid; i < 64 * 32; i += 256) {
        int row = i >> 5, c = i & 31;
        int n = min(m0 + row, Nn - 1);
        float v = (c < 6) ? rbf[(size_t)n * 6 + c] : 0.f;
        L[row * 136 + c] = f2bf(v);
    }
    __syncthreads();
    zacc(acc);
    gemm64<32, 136, 32>(L, Wp2t, 0, acc);
    store_acc(acc, P2, m0, Nn);
}

// ---------------- k_quadagg: CSR owner-computes quad reduction (zero atomics) --------
__global__ __launch_bounds__(256) void k_quadagg(
    const unsigned short* __restrict__ P1, const unsigned short* __restrict__ P2,
    const unsigned short* __restrict__ qfeat, const int* __restrict__ lq,
    const int* __restrict__ rowend, const int* __restrict__ rowcnt,
    const float* __restrict__ We1a_raw, const float* __restrict__ b_e1a,
    unsigned short* __restrict__ Rb)
{
    __shared__ float W34[12 * 128];
    __shared__ float bia[128];
    const int tid = threadIdx.x;
    for (int i = tid; i < 12 * 128; i += 256) W34[i] = We1a_raw[134 * 128 + i];
    if (tid < 128) bia[tid] = b_e1a[tid];
    __syncthreads();
    const int nd = tid >> 4;
    const int c0 = (tid & 15) * 8;
    const int n = blockIdx.x * 16 + nd;
    const int end = rowend[n];
    const int beg = end - rowcnt[n];
    float base[8];
    {
        uint4 p2v = *(const uint4*)&P2[(size_t)n * 128 + c0];
        const unsigned short* pp = (const unsigned short*)&p2v;
#pragma unroll
        for (int k = 0; k < 8; ++k) base[k] = bia[c0 + k] + bf2f(pp[k]);
    }
    float acc[8];
#pragma unroll
    for (int k = 0; k < 8; ++k) acc[k] = 0.f;
    for (int e = beg; e < end; ++e) {
        int l = lq[e];
        uint4 a = *(const uint4*)&P1[(size_t)l * 128 + c0];
        uint2 f0 = *(const uint2*)&qfeat[(size_t)e * 12];
        uint2 f1 = *(const uint2*)&qfeat[(size_t)e * 12 + 4];
        uint2 f2 = *(const uint2*)&qfeat[(size_t)e * 12 + 8];
        const unsigned short* q0 = (const unsigned short*)&f0;
        const unsigned short* q1 = (const unsigned short*)&f1;
        const unsigned short* q2 = (const unsigned short*)&f2;
        float qv[12] = {bf2f(q0[0]), bf2f(q0[1]), bf2f(q0[2]), bf2f(q0[3]),
                        bf2f(q1[0]), bf2f(q1[1]), bf2f(q1[2]), bf2f(q1[3]),
                        bf2f(q2[0]), bf2f(q2[1]), bf2f(q2[2]), bf2f(q2[3])};
        const unsigned short* ap = (const unsigned short*)&a;
        float t[8];
#pragma unroll
        for (int k = 0; k < 8; ++k) t[k] = base[k] + bf2f(ap[k]);
#pragma unroll
        for (int kk = 0; kk < 12; ++kk) {
            float q_ = qv[kk];
#pragma unroll
            for (int k = 0; k < 8; ++k)
                t[k] = fmaf(q_, W34[kk * 128 + c0 + k], t[k]);
        }
#pragma unroll
        for (int k = 0; k < 8; ++k) acc[k] += fmaxf(t[k], 0.f);
    }
    unsigned short ov[8];
#pragma unroll
    for (int k = 0; k < 8; ++k) ov[k] = f2bf(acc[k]);
    *(uint4*)&Rb[(size_t)n * 128 + c0] = *(uint4*)ov;
}

// ---------------- k_edgeagg: CSR owner-computes edge reduction (zero atomics) --------
__global__ __launch_bounds__(256) void k_edgeagg(
    const unsigned short* __restrict__ Z1, const unsigned short* __restrict__ Z2,
    const int* __restrict__ srcs,
    const int* __restrict__ rowend, const int* __restrict__ rowcnt,
    const float* __restrict__ b_e2a,
    unsigned short* __restrict__ Rb)
{
    const int tid = threadIdx.x;
    const int nd = tid >> 4;
    const int c0 = (tid & 15) * 8;
    const int n = blockIdx.x * 16 + nd;
    const int end = rowend[n];
    const int beg = end - rowcnt[n];
    float z2b[8];
    {
        uint4 zv = *(const uint4*)&Z2[(size_t)n * 128 + c0];
        const unsigned short* zp = (const unsigned short*)&zv;
        float4 b0 = *(const float4*)&b_e2a[c0];
        float4 b1 = *(const float4*)&b_e2a[c0 + 4];
        z2b[0] = b0.x + bf2f(zp[0]); z2b[1] = b0.y + bf2f(zp[1]);
        z2b[2] = b0.z + bf2f(zp[2]); z2b[3] = b0.w + bf2f(zp[3]);
        z2b[4] = b1.x + bf2f(zp[4]); z2b[5] = b1.y + bf2f(zp[5]);
        z2b[6] = b1.z + bf2f(zp[6]); z2b[7] = b1.w + bf2f(zp[7]);
    }
    float acc[8];
#pragma unroll
    for (int k = 0; k < 8; ++k) acc[k] = 0.f;
    int e = beg;
    for (; e + 2 <= end; e += 2) {
        int s0 = srcs[e], s1 = srcs[e + 1];
        uint4 a0 = *(const uint4*)&Z1[(size_t)s0 * 128 + c0];
        uint4 a1 = *(const uint4*)&Z1[(size_t)s1 * 128 + c0];
        const unsigned short* p0 = (const unsigned short*)&a0;
        const unsigned short* p1 = (const unsigned short*)&a1;
#pragma unroll
        for (int k = 0; k < 8; ++k) acc[k] += fmaxf(z2b[k] + bf2f(p0[k]), 0.f);
#pragma unroll
        for (int k = 0; k < 8; ++k) acc[k] += fmaxf(z2b[k] + bf2f(p1[k]), 0.f);
    }
    if (e < end) {
        int s0 = srcs[e];
        uint4 a0 = *(const uint4*)&Z1[(size_t)s0 * 128 + c0];
        const unsigned short* p0 = (const unsigned short*)&a0;
#pragma unroll
        for (int k = 0; k < 8; ++k) acc[k] += fmaxf(z2b[k] + bf2f(p0[k]), 0.f);
    }
    unsigned short ov[8];
#pragma unroll
    for (int k = 0; k < 8; ++k) ov[k] = f2bf(acc[k]);
    *(uint4*)&Rb[(size_t)n * 128 + c0] = *(uint4*)ov;
}

// ---------------- k_agg2z: T = Rq*We1b + cntq*b_e1b ; Z2 = T*We2a[128:256] ----------------
__global__ __launch_bounds__(256) void k_agg2z(
    const unsigned short* __restrict__ Rb, const int* __restrict__ cntq,
    const unsigned short* __restrict__ wb, const float* __restrict__ b_e1b,
    unsigned short* __restrict__ Z2)
{
    __shared__ unsigned short L[64 * 136];
    __shared__ int rc[64];
    const int m0 = blockIdx.x * 64;
    const int tid = threadIdx.x;
    const unsigned short* We1bt = wb + 20480;
    const unsigned short* We2at = wb + 36864;
    if (tid < 64) rc[tid] = (m0 + tid < Nn) ? cntq[m0 + tid] : 0;
    for (int i = tid; i < 64 * 16; i += 256) {
        int row = i >> 4, ch = i & 15;
        int n = min(m0 + row, Nn - 1);
        *(uint4*)&L[row * 136 + ch * 8] = *(const uint4*)&Rb[(size_t)n * 128 + ch * 8];
    }
    __syncthreads();
    f32x4 acc[4][2];
    zacc(acc);
    gemm64<128, 136, 128>(L, We1bt, 0, acc);
    __syncthreads();
    {
        const int lane = tid & 63;
        const int nb = (tid >> 6) * 32;
        const int rA = lane & 15, kg = lane >> 4;
#pragma unroll
        for (int rt = 0; rt < 4; ++rt)
#pragma unroll
            for (int ct = 0; ct < 2; ++ct) {
                int col = nb + ct * 16 + rA;
                float bias = b_e1b[col];
#pragma unroll
                for (int i = 0; i < 4; ++i) {
                    int row = rt * 16 + kg * 4 + i;
                    L[row * 136 + col] = f2bf(acc[rt][ct][i] + (float)rc[row] * bias);
                }
            }
    }
    __syncthreads();
    zacc(acc);
    gemm64<128, 136, 256>(L, We2at, 128, acc);
    store_acc(acc, Z2, m0, Nn);
}

// ---------------- k_nodeNew: in-place h update ----------------
__global__ __launch_bounds__(256) void k_nodeNew(
    const unsigned short* __restrict__ Rb, const int* __restrict__ deg,
    const unsigned short* __restrict__ wb,
    const float* __restrict__ b_e2b, const float* __restrict__ b_na,
    const float* __restrict__ b_nb,
    unsigned short* __restrict__ hb)
{
    __shared__ unsigned short L[64 * 136];
    __shared__ int rc[64];
    const int m0 = blockIdx.x * 64;
    const int tid = threadIdx.x;
    const unsigned short* We2bt = wb + 69632;
    const unsigned short* Wnat  = wb + 86016;
    const unsigned short* Wnbt  = wb + 118784;
    const int lane = tid & 63;
    const int nb = (tid >> 6) * 32;
    const int rA = lane & 15, kg = lane >> 4;
    if (tid < 64) rc[tid] = (m0 + tid < Nn) ? deg[m0 + tid] : 0;
    for (int i = tid; i < 64 * 16; i += 256) {
        int row = i >> 4, ch = i & 15;
        int n = min(m0 + row, Nn - 1);
        *(uint4*)&L[row * 136 + ch * 8] = *(const uint4*)&Rb[(size_t)n * 128 + ch * 8];
    }
    __syncthreads();
    f32x4 acc[4][2];
    zacc(acc);
    gemm64<128, 136, 128>(L, We2bt, 0, acc);     // U = Re*We2b
    __syncthreads();
#pragma unroll
    for (int rt = 0; rt < 4; ++rt)
#pragma unroll
        for (int ct = 0; ct < 2; ++ct) {
            int col = nb + ct * 16 + rA;
            float bias = b_e2b[col];
#pragma unroll
            for (int i = 0; i < 4; ++i) {
                int row = rt * 16 + kg * 4 + i;
                L[row * 136 + col] = f2bf(acc[rt][ct][i] + (float)rc[row] * bias);
            }
        }
    __syncthreads();
    f32x4 acc2[4][2];
    zacc(acc2);
    gemm64<128, 136, 256>(L, Wnat, 128, acc2);   // V = U*Wbot_n
    __syncthreads();
    for (int i = tid; i < 64 * 16; i += 256) {
        int row = i >> 4, ch = i & 15;
        int n = min(m0 + row, Nn - 1);
        *(uint4*)&L[row * 136 + ch * 8] = *(const uint4*)&hb[(size_t)n * 128 + ch * 8];
    }
    __syncthreads();
    gemm64<128, 136, 256>(L, Wnat, 0, acc2);     // V += h*Wtop_n
    __syncthreads();
#pragma unroll
    for (int rt = 0; rt < 4; ++rt)
#pragma unroll
        for (int ct = 0; ct < 2; ++ct) {
            int col = nb + ct * 16 + rA;
            float bias = b_na[col];
#pragma unroll
            for (int i = 0; i < 4; ++i) {
                int row = rt * 16 + kg * 4 + i;
                L[row * 136 + col] = f2bf(fmaxf(acc2[rt][ct][i] + bias, 0.f));
            }
        }
    __syncthreads();
    zacc(acc);
    gemm64<128, 136, 128>(L, Wnbt, 0, acc);      // hidden*Wnb
#pragma unroll
    for (int rt = 0; rt < 4; ++rt)
#pragma unroll
        for (int ct = 0; ct < 2; ++ct) {
            int col = nb + ct * 16 + rA;
            float bias = b_nb[col];
#pragma unroll
            for (int i = 0; i < 4; ++i) {
                int n = m0 + rt * 16 + kg * 4 + i;
                if (n < Nn)
                    hb[(size_t)n * 128 + col] = f2bf(acc[rt][ct][i] + bias);
            }
        }
}

// ---------------- global mean pool: run-length segmented reduction ----------------
__global__ __launch_bounds__(256) void k_pool(const unsigned short* __restrict__ hb,
                                              const int* __restrict__ batch,
                                              float* __restrict__ pooled,
                                              float* __restrict__ cntg) {
    __shared__ int bseg[200];
    constexpr int CH = 196;
    const int start = blockIdx.x * CH;
    const int end = min(start + CH, Nn);
    if (start >= end) return;
    const int tid = threadIdx.x;
    for (int i = tid; i < end - start; i += 256) bseg[i] = batch[start + i];
    __syncthreads();
    const int j = tid & 127;
    const int rh = tid >> 7;
    float acc = 0.f, cacc = 0.f;
    int cur = -1;
    for (int n = start + rh; n < end; n += 2) {
        int g = bseg[n - start];
        if (g != cur) {
            if (cur >= 0) {
                atomicAdd(&pooled[cur * Hh + j], acc);
                if (j == 0) atomicAdd(&cntg[cur], cacc);
            }
            cur = g; acc = 0.f; cacc = 0.f;
        }
        acc += bf2f(hb[(size_t)n * Hh + j]);
        cacc += 1.f;
    }
    if (cur >= 0) {
        atomicAdd(&pooled[cur * Hh + j], acc);
        if (j == 0) atomicAdd(&cntg[cur], cacc);
    }
}

// ---------------- final per-graph MLP ----------------
__global__ __launch_bounds__(128) void k_final(
    const float* __restrict__ pooled, const float* __restrict__ cntg,
    const float* __restrict__ Woa, const float* __restrict__ boa,
    const float* __restrict__ Wob, const float* __restrict__ bob,
    float* __restrict__ out)
{
    __shared__ float p[128];
    __shared__ float t[128];
    __shared__ float red[128];
    const int g = blockIdx.x;
    const int j = threadIdx.x;
    float c = fmaxf(cntg[g], 1.f);
    p[j] = fmaxf(pooled[g * Hh + j] / c, 0.f);
    __syncthreads();
    float acc = boa[j];
    for (int d = 0; d < Hh; ++d) acc = fmaf(p[d], Woa[d * Hh + j], acc);
    t[j] = fmaxf(acc, 0.f);
    __syncthreads();
    red[j] = t[j] * Wob[j];
    __syncthreads();
    for (int s = 64; s > 0; s >>= 1) {
        if (j < s) red[j] += red[j + s];
        __syncthreads();
    }
    if (j == 0) out[g] = red[0] + bob[0];
}

extern "C" void kernel_launch(void* const* d_in, const int* in_sizes, int n_in,
                              void* d_out, int out_size, void* d_ws, size_t ws_size,
                              hipStream_t stream) {
    const float* x     = (const float*)d_in[0];
    const float* rbf   = (const float*)d_in[1];
    const float* cbf   = (const float*)d_in[2];
    const float* sbf   = (const float*)d_in[3];
    const int*   eidx  = (const int*)d_in[4];
    const int*   l_idx = (const int*)d_in[5];
    const int*   k_idx = (const int*)d_in[6];
    const int*   batch = (const int*)d_in[7];
    const float* W_e1a = (const float*)d_in[8];
    const float* b_e1a = (const float*)d_in[9];
    const float* W_e1b = (const float*)d_in[10];
    const float* b_e1b = (const float*)d_in[11];
    const float* W_e2a = (const float*)d_in[12];
    const float* b_e2a = (const float*)d_in[13];
    const float* W_e2b = (const float*)d_in[14];
    const float* b_e2b = (const float*)d_in[15];
    const float* W_na  = (const float*)d_in[16];
    const float* b_na  = (const float*)d_in[17];
    const float* W_nb  = (const float*)d_in[18];
    const float* b_nb  = (const float*)d_in[19];
    const float* W_oa  = (const float*)d_in[20];
    const float* b_oa  = (const float*)d_in[21];
    const float* W_ob  = (const float*)d_in[22];
    const float* b_ob  = (const float*)d_in[23];

    const int* src = eidx;
    const int* dst = eidx + Ee;

    const size_t NHb = (size_t)Nn * Hh * sizeof(unsigned short);
    char* w = (char*)d_ws;
    unsigned short* hb  = (unsigned short*)w; w += NHb;
    unsigned short* P1  = (unsigned short*)w; w += NHb;
    unsigned short* P2  = (unsigned short*)w; w += NHb;
    unsigned short* Z1  = (unsigned short*)w; w += NHb;
    unsigned short* Z2  = (unsigned short*)w; w += NHb;
    unsigned short* Rb  = (unsigned short*)w; w += NHb;
    float* pooled = (float*)w; w += (size_t)Gg * Hh * sizeof(float);
    float* cntg   = (float*)w; w += (size_t)Gg * sizeof(float);
    int*   lq     = (int*)w;   w += (size_t)Qq * sizeof(int);
    unsigned short* qfeat = (unsigned short*)w; w += (size_t)Qq * 12 * sizeof(unsigned short);
    int*   srcs_e = (int*)w;   w += (size_t)Ee * sizeof(int);
    int*   hist_e = (int*)w;   w += (size_t)Nn * sizeof(int);
    int*   hist_q = (int*)w;   w += (size_t)Nn * sizeof(int);
    int*   cur_e  = (int*)w;   w += (size_t)Nn * sizeof(int);
    int*   cur_q  = (int*)w;   w += (size_t)Nn * sizeof(int);
    int*   bsum_e = (int*)w;   w += 64 * sizeof(int);
    int*   bsum_q = (int*)w;   w += 64 * sizeof(int);
    unsigned short* wbuf = (unsigned short*)w;            // 3 x 135168 bf16

    const size_t LSTRIDE = 135168;

    // --- counting sort: edges by dst (hist_e kept = in-degree) ---
    hipMemsetAsync(hist_e, 0, Nn * sizeof(int), stream);
    k_hist<<<(Ee + 255) / 256, 256, 0, stream>>>(dst, Ee, Nn, hist_e);
    k_scanA<<<NSCB, 1024, 0, stream>>>(hist_e, cur_e, bsum_e);
    k_scanB<<<1, 64, 0, stream>>>(bsum_e);
    k_scanC<<<NSCB, 1024, 0, stream>>>(cur_e, bsum_e);
    k_scatter_e<<<(Ee + 255) / 256, 256, 0, stream>>>(dst, src, cur_e, srcs_e);
    // --- counting sort: quads by k_idx (compaction k<Nn); payload l + bf16 feat ---
    hipMemsetAsync(hist_q, 0, Nn * sizeof(int), stream);
    k_hist<<<(Qq + 255) / 256, 256, 0, stream>>>(k_idx, Qq, Nn, hist_q);
    k_scanA<<<NSCB, 1024, 0, stream>>>(hist_q, cur_q, bsum_q);
    k_scanB<<<1, 64, 0, stream>>>(bsum_q);
    k_scanC<<<NSCB, 1024, 0, stream>>>(cur_q, bsum_q);
    k_scatter_q<<<(Qq + 255) / 256, 256, 0, stream>>>(k_idx, l_idx, cbf, sbf,
        cur_q, lq, qfeat);

    k_h0<<<(Nn * Hh + 255) / 256, 256, 0, stream>>>(x, hb);

    {
        dim3 g((135168 + 255) / 256, 3);
        k_wtall<<<g, 256, 0, stream>>>(W_e1a, W_e1b, W_e2a, W_e2b, W_na, W_nb, wbuf);
    }

    for (int p = 0; p < 3; ++p) {
        const unsigned short* wb = wbuf + p * LSTRIDE;
        k_pre<<<NB64, 256, 0, stream>>>(hb, rbf, wb, P1, Z1, P2);
        k_quadagg<<<Nn / 16, 256, 0, stream>>>(P1, P2, qfeat, lq,
            cur_q, hist_q, W_e1a + (size_t)p * 146 * 128, b_e1a + (size_t)p * 128, Rb);
        k_agg2z<<<NB64, 256, 0, stream>>>(Rb, hist_q, wb, b_e1b + (size_t)p * 128, Z2);
        k_edgeagg<<<Nn / 16, 256, 0, stream>>>(Z1, Z2, srcs_e, cur_e, hist_e,
            b_e2a + (size_t)p * 128, Rb);
        k_nodeNew<<<NB64, 256, 0, stream>>>(Rb, hist_e, wb,
            b_e2b + (size_t)p * 128, b_na + (size_t)p * 128, b_nb + (size_t)p * 128,
            hb);
    }
    hipMemsetAsync(pooled, 0, (size_t)Gg * Hh * sizeof(float), stream);
    hipMemsetAsync(cntg, 0, (size_t)Gg * sizeof(float), stream);
    k_pool<<<(Nn + 195) / 196, 256, 0, stream>>>(hb, batch, pooled, cntg);
    k_final<<<Gg, 128, 0, stream>>>(pooled, cntg, W_oa, b_oa, W_ob, b_ob, (float*)d_out);
}